// Round 1
// baseline (881.878 us; speedup 1.0000x reference)
//
#include <hip/hip_runtime.h>
#include <hip/hip_fp16.h>

#define BB 4
#define HH 240
#define WW 1216
#define NIMG (HH * WW)
#define NPIX (BB * NIMG)

// ---------------------------------------------------------------------------
// Re-permute conv weights: W_oa[o][c][t] (o<24, c<8, t<9) -> Wre[c][t][o]
// so the conv inner loop reads 24 contiguous (wave-uniform) floats.
// ---------------------------------------------------------------------------
__global__ __launch_bounds__(256) void k_permute(const float* __restrict__ W_oa,
                                                 float* __restrict__ Wre) {
    for (int i = threadIdx.x; i < 24 * 8 * 9; i += 256) {
        int o = i / 72;
        int r = i - o * 72;
        int c = r / 9;
        int t = r - c * 9;
        Wre[(c * 9 + t) * 24 + o] = W_oa[i];
    }
}

// Bilinear sample of confidence with zero-outside-border semantics
// (matches reference: valid per-corner, clip gather index, where(valid, v, 0))
__device__ __forceinline__ float conf_corner(const float* __restrict__ cb,
                                             float yc, float xc) {
    bool valid = (yc >= 0.f) && (yc <= (float)(HH - 1)) &&
                 (xc >= 0.f) && (xc <= (float)(WW - 1));
    int yi = (int)fminf(fmaxf(yc, 0.f), (float)(HH - 1));
    int xi = (int)fminf(fmaxf(xc, 0.f), (float)(WW - 1));
    float v = cb[yi * WW + xi];
    return valid ? v : 0.f;
}

// ---------------------------------------------------------------------------
// Precompute kernel: 3x3 conv head -> offsets/affinities -> TGASS scaling ->
// confidence modulation -> normalization -> per-tap {base index, 4 weights}.
// Also writes F0 = mix(feat_init) (sparse-fix injected).
// ---------------------------------------------------------------------------
__global__ __launch_bounds__(256) void k_precompute(
    const float* __restrict__ guid, const float* __restrict__ conf,
    const float* __restrict__ feat_init, const float* __restrict__ feat_fix,
    const float* __restrict__ Wre, const float* __restrict__ b_oa,
    const float* __restrict__ aff_scale,
    float* __restrict__ F0, int* __restrict__ IDX, float4* __restrict__ W4) {
    int p = blockIdx.x * 256 + threadIdx.x;
    if (p >= NPIX) return;
    int x = p % WW;
    int y = (p / WW) % HH;
    int b = p / NIMG;

    // ---- 3x3 conv, 8 in-ch -> 24 out-ch, zero pad ----
    float acc[24];
#pragma unroll
    for (int o = 0; o < 24; o++) acc[o] = b_oa[o];

    const float* gb = guid + (size_t)b * 8 * NIMG;
#pragma unroll 1
    for (int c = 0; c < 8; c++) {
        const float* gc = gb + c * NIMG;
#pragma unroll
        for (int t = 0; t < 9; t++) {
            int dy = t / 3 - 1;
            int dx = t - (t / 3) * 3 - 1;
            int yy = y + dy, xx = x + dx;
            float gv = (yy >= 0 && yy < HH && xx >= 0 && xx < WW)
                           ? gc[yy * WW + xx] : 0.f;
            const float* wp = Wre + (c * 9 + t) * 24;
#pragma unroll
            for (int o = 0; o < 24; o++) acc[o] = fmaf(gv, wp[o], acc[o]);
        }
    }

    // ---- TGASS affinity + confidence modulation ----
    float ascale = aff_scale[0] + 1e-8f;
    const float* cb = conf + (size_t)b * NIMG;
    float aff[8], ofy[8], ofx[8];
    float asum = 0.f;
#pragma unroll
    for (int k = 0; k < 8; k++) {
        float dy = acc[k];
        float dx = acc[8 + k];
        ofy[k] = dy;
        ofx[k] = dx;
        float a = tanhf(acc[16 + k]) / ascale;
        float ys = dy + (float)y;
        float xs = dx + (float)x;
        float y0f = floorf(ys), x0f = floorf(xs);
        float wy = ys - y0f, wx = xs - x0f;
        float v = conf_corner(cb, y0f, x0f) * (1.f - wy) * (1.f - wx)
                + conf_corner(cb, y0f, x0f + 1.f) * (1.f - wy) * wx
                + conf_corner(cb, y0f + 1.f, x0f) * wy * (1.f - wx)
                + conf_corner(cb, y0f + 1.f, x0f + 1.f) * wy * wx;
        a *= v;
        aff[k] = a;
        asum += fabsf(a);
    }

    // ---- TGASS normalization + reference affinity ----
    float s = fmaxf(asum + 1e-4f, 1.0f);
    float inv = 1.f / s;
    float tot = 0.f;
#pragma unroll
    for (int k = 0; k < 8; k++) {
        aff[k] *= inv;
        tot += aff[k];
    }
    float aref = 1.0f - tot;

    // ---- per-tap base index + premultiplied bilinear*affinity weights ----
#pragma unroll
    for (int kk = 0; kk < 9; kk++) {
        float a, dy, dx;
        if (kk < 4)       { a = aff[kk];     dy = ofy[kk];     dx = ofx[kk]; }
        else if (kk == 4) { a = aref;        dy = 0.f;         dx = 0.f; }
        else              { a = aff[kk - 1]; dy = ofy[kk - 1]; dx = ofx[kk - 1]; }
        int kh = kk / 3 - 1;
        int kw = kk - (kk / 3) * 3 - 1;
        float ys = (dy + (float)kh) + (float)y;
        float xs = (dx + (float)kw) + (float)x;
        float y0f = floorf(ys), x0f = floorf(xs);
        float wy = ys - y0f, wx = xs - x0f;
        // clamp to a small range so the int cast is safe; preserves validity
        float y0c = fminf(fmaxf(y0f, -2.f), (float)HH);
        float x0c = fminf(fmaxf(x0f, -2.f), (float)WW);
        int y0 = (int)y0c, x0 = (int)x0c;
        int by = min(max(y0, 0), HH - 2);
        int bx = min(max(x0, 0), WW - 2);
        // y-direction contributions mapped onto slots (by, by+1)
        float cy0 = 0.f, cy1 = 0.f;
        if (y0 >= 0 && y0 <= HH - 1) { if (y0 == by) cy0 = 1.f - wy; else cy1 = 1.f - wy; }
        if (y0 + 1 >= 0 && y0 + 1 <= HH - 1) { if (y0 + 1 == by) cy0 = wy; else cy1 = wy; }
        float cx0 = 0.f, cx1 = 0.f;
        if (x0 >= 0 && x0 <= WW - 1) { if (x0 == bx) cx0 = 1.f - wx; else cx1 = 1.f - wx; }
        if (x0 + 1 >= 0 && x0 + 1 <= WW - 1) { if (x0 + 1 == bx) cx0 = wx; else cx1 = wx; }

        int base = b * NIMG + by * WW + bx;
        float4 w;
        w.x = cy0 * cx0 * a;
        w.y = cy0 * cx1 * a;
        w.z = cy1 * cx0 * a;
        w.w = cy1 * cx1 * a;
        IDX[kk * NPIX + p] = base;
        W4[kk * NPIX + p] = w;
    }

    // ---- F0 = sparse-fix-injected initial feat ----
    float ff = feat_fix[p];
    F0[p] = (ff > 0.f) ? ff : feat_init[p];
}

// ---------------------------------------------------------------------------
// One propagation step. Branch-free 9-tap x 4-corner weighted gather.
// Non-final steps write the sparse-fix-injected value; final writes raw sum.
// ---------------------------------------------------------------------------
__global__ __launch_bounds__(256) void k_prop(
    const float* __restrict__ Fin, const int* __restrict__ IDX,
    const float4* __restrict__ W4, const float* __restrict__ feat_fix,
    float* __restrict__ Fout, int last) {
    int p = blockIdx.x * 256 + threadIdx.x;
    if (p >= NPIX) return;
    float s = 0.f;
#pragma unroll
    for (int k = 0; k < 9; k++) {
        int base = IDX[k * NPIX + p];
        float4 w = W4[k * NPIX + p];
        float f00 = Fin[base];
        float f01 = Fin[base + 1];
        float f10 = Fin[base + WW];
        float f11 = Fin[base + WW + 1];
        s = fmaf(f00, w.x, s);
        s = fmaf(f01, w.y, s);
        s = fmaf(f10, w.z, s);
        s = fmaf(f11, w.w, s);
    }
    if (last) {
        Fout[p] = s;
    } else {
        float ff = feat_fix[p];
        Fout[p] = (ff > 0.f) ? ff : s;
    }
}

extern "C" void kernel_launch(void* const* d_in, const int* in_sizes, int n_in,
                              void* d_out, int out_size, void* d_ws, size_t ws_size,
                              hipStream_t stream) {
    const float* feat_init  = (const float*)d_in[0];
    const float* guidance   = (const float*)d_in[1];
    const float* confidence = (const float*)d_in[2];
    const float* feat_fix   = (const float*)d_in[3];
    const float* W_oa       = (const float*)d_in[4];
    const float* b_oa       = (const float*)d_in[5];
    const float* aff_scale  = (const float*)d_in[6];

    char* ws = (char*)d_ws;
    size_t off = 0;
    auto carve = [&](size_t bytes) -> char* {
        char* ptr = ws + off;
        off += (bytes + 511) & ~(size_t)511;
        return ptr;
    };
    float*  Wre = (float*)carve(24 * 8 * 9 * sizeof(float));
    float*  F0  = (float*)carve((size_t)NPIX * sizeof(float));
    float*  F1  = (float*)carve((size_t)NPIX * sizeof(float));
    int*    IDX = (int*)carve((size_t)9 * NPIX * sizeof(int));
    float4* W4  = (float4*)carve((size_t)9 * NPIX * sizeof(float4));
    (void)ws_size; (void)in_sizes; (void)n_in; (void)out_size;

    int grid = (NPIX + 255) / 256;
    hipLaunchKernelGGL(k_permute, dim3(1), dim3(256), 0, stream, W_oa, Wre);
    hipLaunchKernelGGL(k_precompute, dim3(grid), dim3(256), 0, stream,
                       guidance, confidence, feat_init, feat_fix, Wre, b_oa,
                       aff_scale, F0, IDX, W4);

    float* bufs[2] = {F0, F1};
    int cur = 0;
    for (int it = 0; it < 18; ++it) {
        int last = (it == 17) ? 1 : 0;
        float* outp = last ? (float*)d_out : bufs[cur ^ 1];
        hipLaunchKernelGGL(k_prop, dim3(grid), dim3(256), 0, stream,
                           bufs[cur], IDX, W4, feat_fix, outp, last);
        cur ^= 1;
    }
}

// Round 2
// 742.859 us; speedup vs baseline: 1.1871x; 1.1871x over previous
//
#include <hip/hip_runtime.h>
#include <hip/hip_fp16.h>

#define BB 4
#define HH 240
#define WW 1216
#define NIMG (HH * WW)
#define NPIX (BB * NIMG)

// Confidence padded with a 2-wide zero border on top/left and 3-wide on
// bottom/right: rows 0,1 and 242,243,244 are zero; real rows at 2..241.
#define CHP 245
#define CWP 1221
#define CIMG (CHP * CWP)

typedef __attribute__((ext_vector_type(4))) _Float16 half4;

// ---------------------------------------------------------------------------
// Re-permute conv weights: W_oa[o][c][t] (o<24, c<8, t<9) -> Wre[c][t][o]
// ---------------------------------------------------------------------------
__global__ __launch_bounds__(256) void k_permute(const float* __restrict__ W_oa,
                                                 float* __restrict__ Wre) {
    for (int i = threadIdx.x; i < 24 * 8 * 9; i += 256) {
        int o = i / 72;
        int r = i - o * 72;
        int c = r / 9;
        int t = r - c * 9;
        Wre[(c * 9 + t) * 24 + o] = W_oa[i];
    }
}

// ---------------------------------------------------------------------------
// Zero-pad confidence: cpad[b][yp][xp] = conf[b][yp-2][xp-2] inside, 0 outside
// ---------------------------------------------------------------------------
__global__ __launch_bounds__(256) void k_padconf(const float* __restrict__ conf,
                                                 float* __restrict__ cpad) {
    int i = blockIdx.x * 256 + threadIdx.x;
    if (i >= BB * CIMG) return;
    int xp = i % CWP;
    int yp = (i / CWP) % CHP;
    int b = i / CIMG;
    float v = 0.f;
    int y = yp - 2, x = xp - 2;
    if (y >= 0 && y < HH && x >= 0 && x < WW) v = conf[b * NIMG + y * WW + x];
    cpad[i] = v;
}

__device__ __forceinline__ float fast_tanh(float x) {
    float xc = fminf(fmaxf(x, -15.f), 15.f);
    float e = __expf(2.f * xc);
    return 1.f - 2.f * __builtin_amdgcn_rcpf(e + 1.f);
}

// ---------------------------------------------------------------------------
// Precompute: conv head -> affinities (fast tanh, padded-conf bilinear) ->
// normalization -> per-tap {base index, 4 premultiplied fp16 weights}, F0.
// ---------------------------------------------------------------------------
__global__ __launch_bounds__(256) void k_precompute(
    const float* __restrict__ guid, const float* __restrict__ cpad,
    const float* __restrict__ feat_init, const float* __restrict__ feat_fix,
    const float* __restrict__ Wre, const float* __restrict__ b_oa,
    const float* __restrict__ aff_scale,
    float* __restrict__ F0, int* __restrict__ IDX, half4* __restrict__ W4) {
    int p = blockIdx.x * 256 + threadIdx.x;
    if (p >= NPIX) return;
    int x = p % WW;
    int y = (p / WW) % HH;
    int b = p / NIMG;

    // ---- 3x3 conv, 8 in-ch -> 24 out-ch, zero pad ----
    float acc[24];
#pragma unroll
    for (int o = 0; o < 24; o++) acc[o] = b_oa[o];

    const float* gb = guid + (size_t)b * 8 * NIMG;
#pragma unroll 1
    for (int c = 0; c < 8; c++) {
        const float* gc = gb + c * NIMG;
#pragma unroll
        for (int t = 0; t < 9; t++) {
            int dy = t / 3 - 1;
            int dx = t - (t / 3) * 3 - 1;
            int yy = y + dy, xx = x + dx;
            float gv = (yy >= 0 && yy < HH && xx >= 0 && xx < WW)
                           ? gc[yy * WW + xx] : 0.f;
            const float* wp = Wre + (c * 9 + t) * 24;
#pragma unroll
            for (int o = 0; o < 24; o++) acc[o] = fmaf(gv, wp[o], acc[o]);
        }
    }

    // ---- TGASS affinity + confidence modulation (padded conf, no branches) --
    float inv_ascale = __builtin_amdgcn_rcpf(aff_scale[0] + 1e-8f);
    const float* cb = cpad + (size_t)b * CIMG;
    float aff[8], ofy[8], ofx[8];
    float asum = 0.f;
#pragma unroll
    for (int k = 0; k < 8; k++) {
        float dy = acc[k];
        float dx = acc[8 + k];
        ofy[k] = dy;
        ofx[k] = dx;
        float a = fast_tanh(acc[16 + k]) * inv_ascale;
        float ys = dy + (float)y;
        float xs = dx + (float)x;
        float y0f = floorf(ys), x0f = floorf(xs);
        float wy = ys - y0f, wx = xs - x0f;
        int ya = (int)(fminf(fmaxf(y0f, -2.f), 241.f)) + 2;
        int yb = (int)(fminf(fmaxf(y0f + 1.f, -2.f), 241.f)) + 2;
        int xa = (int)(fminf(fmaxf(x0f, -2.f), 1217.f)) + 2;
        int xb = (int)(fminf(fmaxf(x0f + 1.f, -2.f), 1217.f)) + 2;
        float v00 = cb[ya * CWP + xa];
        float v01 = cb[ya * CWP + xb];
        float v10 = cb[yb * CWP + xa];
        float v11 = cb[yb * CWP + xb];
        float v = (v00 * (1.f - wx) + v01 * wx) * (1.f - wy)
                + (v10 * (1.f - wx) + v11 * wx) * wy;
        a *= v;
        aff[k] = a;
        asum += fabsf(a);
    }

    // ---- TGASS normalization + reference affinity ----
    float s = fmaxf(asum + 1e-4f, 1.0f);
    float inv = __builtin_amdgcn_rcpf(s);
    float tot = 0.f;
#pragma unroll
    for (int k = 0; k < 8; k++) {
        aff[k] *= inv;
        tot += aff[k];
    }
    float aref = 1.0f - tot;

    // ---- per-tap base index + premultiplied bilinear*affinity weights ----
#pragma unroll
    for (int kk = 0; kk < 9; kk++) {
        float a, dy, dx;
        if (kk < 4)       { a = aff[kk];     dy = ofy[kk];     dx = ofx[kk]; }
        else if (kk == 4) { a = aref;        dy = 0.f;         dx = 0.f; }
        else              { a = aff[kk - 1]; dy = ofy[kk - 1]; dx = ofx[kk - 1]; }
        int kh = kk / 3 - 1;
        int kw = kk - (kk / 3) * 3 - 1;
        float ys = (dy + (float)kh) + (float)y;
        float xs = (dx + (float)kw) + (float)x;
        float y0f = floorf(ys), x0f = floorf(xs);
        float wy = ys - y0f, wx = xs - x0f;
        float y0c = fminf(fmaxf(y0f, -2.f), (float)HH);
        float x0c = fminf(fmaxf(x0f, -2.f), (float)WW);
        int y0 = (int)y0c, x0 = (int)x0c;
        int by = min(max(y0, 0), HH - 2);
        int bx = min(max(x0, 0), WW - 2);
        float cy0 = 0.f, cy1 = 0.f;
        if (y0 >= 0 && y0 <= HH - 1) { if (y0 == by) cy0 = 1.f - wy; else cy1 = 1.f - wy; }
        if (y0 + 1 >= 0 && y0 + 1 <= HH - 1) { if (y0 + 1 == by) cy0 = wy; else cy1 = wy; }
        float cx0 = 0.f, cx1 = 0.f;
        if (x0 >= 0 && x0 <= WW - 1) { if (x0 == bx) cx0 = 1.f - wx; else cx1 = 1.f - wx; }
        if (x0 + 1 >= 0 && x0 + 1 <= WW - 1) { if (x0 + 1 == bx) cx0 = wx; else cx1 = wx; }

        int base = b * NIMG + by * WW + bx;
        half4 hw;
        hw.x = (_Float16)(cy0 * cx0 * a);
        hw.y = (_Float16)(cy0 * cx1 * a);
        hw.z = (_Float16)(cy1 * cx0 * a);
        hw.w = (_Float16)(cy1 * cx1 * a);
        IDX[kk * NPIX + p] = base;
        W4[kk * NPIX + p] = hw;
    }

    // ---- F0 = sparse-fix-injected initial feat ----
    float ff = feat_fix[p];
    F0[p] = (ff > 0.f) ? ff : feat_init[p];
}

// ---------------------------------------------------------------------------
// One propagation step: 9 taps x 4 corners, fp16 premultiplied weights.
// ---------------------------------------------------------------------------
__global__ __launch_bounds__(256) void k_prop(
    const float* __restrict__ Fin, const int* __restrict__ IDX,
    const half4* __restrict__ W4, const float* __restrict__ feat_fix,
    float* __restrict__ Fout, int last) {
    int p = blockIdx.x * 256 + threadIdx.x;
    if (p >= NPIX) return;
    float s = 0.f;
#pragma unroll
    for (int k = 0; k < 9; k++) {
        int base = IDX[k * NPIX + p];
        half4 w = W4[k * NPIX + p];
        float f00 = Fin[base];
        float f01 = Fin[base + 1];
        float f10 = Fin[base + WW];
        float f11 = Fin[base + WW + 1];
        s = fmaf(f00, (float)w.x, s);
        s = fmaf(f01, (float)w.y, s);
        s = fmaf(f10, (float)w.z, s);
        s = fmaf(f11, (float)w.w, s);
    }
    if (last) {
        Fout[p] = s;
    } else {
        float ff = feat_fix[p];
        Fout[p] = (ff > 0.f) ? ff : s;
    }
}

extern "C" void kernel_launch(void* const* d_in, const int* in_sizes, int n_in,
                              void* d_out, int out_size, void* d_ws, size_t ws_size,
                              hipStream_t stream) {
    const float* feat_init  = (const float*)d_in[0];
    const float* guidance   = (const float*)d_in[1];
    const float* confidence = (const float*)d_in[2];
    const float* feat_fix   = (const float*)d_in[3];
    const float* W_oa       = (const float*)d_in[4];
    const float* b_oa       = (const float*)d_in[5];
    const float* aff_scale  = (const float*)d_in[6];

    char* ws = (char*)d_ws;
    size_t off = 0;
    auto carve = [&](size_t bytes) -> char* {
        char* ptr = ws + off;
        off += (bytes + 511) & ~(size_t)511;
        return ptr;
    };
    float*  Wre  = (float*)carve(24 * 8 * 9 * sizeof(float));
    float*  F0   = (float*)carve((size_t)NPIX * sizeof(float));
    float*  F1   = (float*)carve((size_t)NPIX * sizeof(float));
    float*  CPAD = (float*)carve((size_t)BB * CIMG * sizeof(float));
    int*    IDX  = (int*)carve((size_t)9 * NPIX * sizeof(int));
    half4*  W4   = (half4*)carve((size_t)9 * NPIX * sizeof(half4));
    (void)ws_size; (void)in_sizes; (void)n_in; (void)out_size;

    int grid = (NPIX + 255) / 256;
    int gridc = (BB * CIMG + 255) / 256;
    hipLaunchKernelGGL(k_permute, dim3(1), dim3(256), 0, stream, W_oa, Wre);
    hipLaunchKernelGGL(k_padconf, dim3(gridc), dim3(256), 0, stream,
                       confidence, CPAD);
    hipLaunchKernelGGL(k_precompute, dim3(grid), dim3(256), 0, stream,
                       guidance, CPAD, feat_init, feat_fix, Wre, b_oa,
                       aff_scale, F0, IDX, W4);

    float* bufs[2] = {F0, F1};
    int cur = 0;
    for (int it = 0; it < 18; ++it) {
        int last = (it == 17) ? 1 : 0;
        float* outp = last ? (float*)d_out : bufs[cur ^ 1];
        hipLaunchKernelGGL(k_prop, dim3(grid), dim3(256), 0, stream,
                           bufs[cur], IDX, W4, feat_fix, outp, last);
        cur ^= 1;
    }
}

// Round 3
// 530.019 us; speedup vs baseline: 1.6639x; 1.4016x over previous
//
#include <hip/hip_runtime.h>
#include <hip/hip_fp16.h>

#define BB 4
#define HH 240
#define WW 1216
#define NIMG (HH * WW)
#define NPIX (BB * NIMG)          // 1,167,360 = 4560 * 256 exactly
#define GRID_MAIN (NPIX / 256)    // 4560

// padded feat layout: image pixel (y,x) lives at (y+2, x+2); 5x5 window of
// pixel (y,x) starts at padded (y, x). Pad cells are only read with weight 0.
#define HHP (HH + 4)              // 244
#define WWP (WW + 4)              // 1220
#define PIMG (HHP * WWP)

// confidence padded with 2 zero rows/cols each side (+1 slack bottom/right)
#define CHP 245
#define CWP 1221
#define CIMG (CHP * CWP)

#define OVF_CAP 65536

struct OvfEntry {                 // exception pixel: full 9-tap data
    int p;
    int base[9];                  // padded-layout corner base indices
    float w[36];                  // 4 premultiplied fp32 weights per tap
};

__device__ __forceinline__ unsigned f2h(float f) {
    union { _Float16 h; unsigned short u; } cv;
    cv.h = (_Float16)f;
    return (unsigned)cv.u;
}
__device__ __forceinline__ float h2f(unsigned short u) {
    union { unsigned short u; _Float16 h; } cv;
    cv.u = u;
    return (float)cv.h;
}

// ---------------------------------------------------------------------------
__global__ __launch_bounds__(256) void k_permute(const float* __restrict__ W_oa,
                                                 float* __restrict__ Wre) {
    for (int i = threadIdx.x; i < 24 * 8 * 9; i += 256) {
        int o = i / 72;
        int r = i - o * 72;
        int c = r / 9;
        int t = r - c * 9;
        Wre[(c * 9 + t) * 24 + o] = W_oa[i];
    }
}

__global__ __launch_bounds__(256) void k_padconf(const float* __restrict__ conf,
                                                 float* __restrict__ cpad) {
    int i = blockIdx.x * 256 + threadIdx.x;
    if (i >= BB * CIMG) return;
    int xp = i % CWP;
    int yp = (i / CWP) % CHP;
    int b = i / CIMG;
    float v = 0.f;
    int y = yp - 2, x = xp - 2;
    if (y >= 0 && y < HH && x >= 0 && x < WW) v = conf[b * NIMG + y * WW + x];
    cpad[i] = v;
}

__device__ __forceinline__ float fast_tanh(float x) {
    float xc = fminf(fmaxf(x, -15.f), 15.f);
    float e = __expf(2.f * xc);
    return 1.f - 2.f * __builtin_amdgcn_rcpf(e + 1.f);
}

// ---------------------------------------------------------------------------
// Precompute: conv head -> affinities -> dense 5x5 window weights (fp16,
// 13 packed uint planes). Non-fitting pixels go to the exception list.
// ---------------------------------------------------------------------------
__global__ __launch_bounds__(256, 2) void k_precompute(
    const float* __restrict__ guid, const float* __restrict__ cpad,
    const float* __restrict__ feat_init, const float* __restrict__ feat_fix,
    const float* __restrict__ Wre, const float* __restrict__ b_oa,
    const float* __restrict__ aff_scale,
    float* __restrict__ F0, unsigned* __restrict__ Wt,
    OvfEntry* __restrict__ ovf, int* __restrict__ ovf_cnt) {
    __shared__ float wl[256 * 27];
    int p = blockIdx.x * 256 + threadIdx.x;
    if (p >= NPIX) return;
    int x = p % WW;
    int y = (p / WW) % HH;
    int b = p / NIMG;

    // ---- 3x3 conv, 8 in-ch -> 24 out-ch, zero pad ----
    float acc[24];
#pragma unroll
    for (int o = 0; o < 24; o++) acc[o] = b_oa[o];

    const float* gb = guid + (size_t)b * 8 * NIMG;
#pragma unroll 1
    for (int c = 0; c < 8; c++) {
        const float* gc = gb + c * NIMG;
#pragma unroll
        for (int t = 0; t < 9; t++) {
            int dy = t / 3 - 1;
            int dx = t - (t / 3) * 3 - 1;
            int yy = y + dy, xx = x + dx;
            float gv = (yy >= 0 && yy < HH && xx >= 0 && xx < WW)
                           ? gc[yy * WW + xx] : 0.f;
            const float* wq = Wre + (c * 9 + t) * 24;
#pragma unroll
            for (int o = 0; o < 24; o++) acc[o] = fmaf(gv, wq[o], acc[o]);
        }
    }

    // ---- TGASS affinity + confidence modulation ----
    float inv_ascale = __builtin_amdgcn_rcpf(aff_scale[0] + 1e-8f);
    const float* cb = cpad + (size_t)b * CIMG;
    float aff[8], ofy[8], ofx[8];
    float asum = 0.f;
#pragma unroll
    for (int k = 0; k < 8; k++) {
        float dy = acc[k];
        float dx = acc[8 + k];
        ofy[k] = dy;
        ofx[k] = dx;
        float a = fast_tanh(acc[16 + k]) * inv_ascale;
        float ys = dy + (float)y;
        float xs = dx + (float)x;
        float y0f = floorf(ys), x0f = floorf(xs);
        float wy = ys - y0f, wx = xs - x0f;
        int ya = (int)(fminf(fmaxf(y0f, -2.f), 241.f)) + 2;
        int yb = (int)(fminf(fmaxf(y0f + 1.f, -2.f), 241.f)) + 2;
        int xa = (int)(fminf(fmaxf(x0f, -2.f), 1217.f)) + 2;
        int xb = (int)(fminf(fmaxf(x0f + 1.f, -2.f), 1217.f)) + 2;
        float v00 = cb[ya * CWP + xa];
        float v01 = cb[ya * CWP + xb];
        float v10 = cb[yb * CWP + xa];
        float v11 = cb[yb * CWP + xb];
        float v = (v00 * (1.f - wx) + v01 * wx) * (1.f - wy)
                + (v10 * (1.f - wx) + v11 * wx) * wy;
        a *= v;
        aff[k] = a;
        asum += fabsf(a);
    }

    float s = fmaxf(asum + 1e-4f, 1.0f);
    float inv = __builtin_amdgcn_rcpf(s);
    float tot = 0.f;
#pragma unroll
    for (int k = 0; k < 8; k++) {
        aff[k] *= inv;
        tot += aff[k];
    }
    float aref = 1.0f - tot;

    float yf = (float)y, xf = (float)x;

    // ---- do all 36 corners land in the 5x5 window? ----
    bool fits = true;
#pragma unroll
    for (int kk = 0; kk < 9; kk++) {
        float dy, dx;
        if (kk < 4)       { dy = ofy[kk];     dx = ofx[kk]; }
        else if (kk == 4) { dy = 0.f;         dx = 0.f; }
        else              { dy = ofy[kk - 1]; dx = ofx[kk - 1]; }
        float ys = yf + (float)(kk / 3 - 1) + dy;
        float xs = xf + (float)(kk - (kk / 3) * 3 - 1) + dx;
        float y0f = floorf(ys), x0f = floorf(xs);
        fits = fits && (y0f >= yf - 2.f) && (y0f <= yf + 1.f)
                    && (x0f >= xf - 2.f) && (x0f <= xf + 1.f);
    }

    float* wp = wl + threadIdx.x * 27;
    if (fits) {
#pragma unroll
        for (int i = 0; i < 25; i++) wp[i] = 0.f;
#pragma unroll
        for (int kk = 0; kk < 9; kk++) {
            float a, dy, dx;
            if (kk < 4)       { a = aff[kk];     dy = ofy[kk];     dx = ofx[kk]; }
            else if (kk == 4) { a = aref;        dy = 0.f;         dx = 0.f; }
            else              { a = aff[kk - 1]; dy = ofy[kk - 1]; dx = ofx[kk - 1]; }
            float ys = yf + (float)(kk / 3 - 1) + dy;
            float xs = xf + (float)(kk - (kk / 3) * 3 - 1) + dx;
            float y0f = floorf(ys), x0f = floorf(xs);
            float wy = ys - y0f, wx = xs - x0f;
            int ry = (int)(y0f - yf + 2.f);
            int rx = (int)(x0f - xf + 2.f);
            bool vy0 = (y0f >= 0.f) && (y0f <= (float)(HH - 1));
            bool vy1 = (y0f + 1.f >= 0.f) && (y0f + 1.f <= (float)(HH - 1));
            bool vx0 = (x0f >= 0.f) && (x0f <= (float)(WW - 1));
            bool vx1 = (x0f + 1.f >= 0.f) && (x0f + 1.f <= (float)(WW - 1));
            float wy0 = 1.f - wy, wx0 = 1.f - wx;
            float w00 = (vy0 && vx0) ? wy0 * wx0 * a : 0.f;
            float w01 = (vy0 && vx1) ? wy0 * wx  * a : 0.f;
            float w10 = (vy1 && vx0) ? wy  * wx0 * a : 0.f;
            float w11 = (vy1 && vx1) ? wy  * wx  * a : 0.f;
            float* cc = wp + (ry * 5 + rx);
            cc[0] += w00;
            cc[1] += w01;
            cc[5] += w10;
            cc[6] += w11;
        }
#pragma unroll
        for (int j = 0; j < 13; j++) {
            unsigned lo = f2h(wp[2 * j]);
            unsigned hi = (j < 12) ? f2h(wp[2 * j + 1]) : 0u;
            Wt[(size_t)j * NPIX + p] = lo | (hi << 16);
        }
    } else {
        int slot = atomicAdd(ovf_cnt, 1);
        if (slot < OVF_CAP) {
            OvfEntry* e = &ovf[slot];
            e->p = p;
#pragma unroll
            for (int kk = 0; kk < 9; kk++) {
                float a, dy, dx;
                if (kk < 4)       { a = aff[kk];     dy = ofy[kk];     dx = ofx[kk]; }
                else if (kk == 4) { a = aref;        dy = 0.f;         dx = 0.f; }
                else              { a = aff[kk - 1]; dy = ofy[kk - 1]; dx = ofx[kk - 1]; }
                float ys = yf + (float)(kk / 3 - 1) + dy;
                float xs = xf + (float)(kk - (kk / 3) * 3 - 1) + dx;
                float y0f = floorf(ys), x0f = floorf(xs);
                float wy = ys - y0f, wx = xs - x0f;
                float y0c = fminf(fmaxf(y0f, -2.f), (float)HH);
                float x0c = fminf(fmaxf(x0f, -2.f), (float)WW);
                int y0 = (int)y0c, x0 = (int)x0c;
                int by = min(max(y0, 0), HH - 2);
                int bx = min(max(x0, 0), WW - 2);
                float cy0 = 0.f, cy1 = 0.f;
                if (y0 >= 0 && y0 <= HH - 1) { if (y0 == by) cy0 = 1.f - wy; else cy1 = 1.f - wy; }
                if (y0 + 1 >= 0 && y0 + 1 <= HH - 1) { if (y0 + 1 == by) cy0 = wy; else cy1 = wy; }
                float cx0 = 0.f, cx1 = 0.f;
                if (x0 >= 0 && x0 <= WW - 1) { if (x0 == bx) cx0 = 1.f - wx; else cx1 = 1.f - wx; }
                if (x0 + 1 >= 0 && x0 + 1 <= WW - 1) { if (x0 + 1 == bx) cx0 = wx; else cx1 = wx; }
                e->base[kk] = (b * HHP + by + 2) * WWP + bx + 2;
                e->w[kk * 4 + 0] = cy0 * cx0 * a;
                e->w[kk * 4 + 1] = cy0 * cx1 * a;
                e->w[kk * 4 + 2] = cy1 * cx0 * a;
                e->w[kk * 4 + 3] = cy1 * cx1 * a;
            }
        }
#pragma unroll
        for (int j = 0; j < 13; j++)
            Wt[(size_t)j * NPIX + p] = (j == 12) ? 0x3C000000u : 0u;
    }

    // ---- F0 = sparse-fix-injected initial feat (padded layout) ----
    float ff = feat_fix[p];
    F0[(b * HHP + y + 2) * WWP + x + 2] = (ff > 0.f) ? ff : feat_init[p];
}

// ---------------------------------------------------------------------------
// One propagation step: dense 5x5 stencil, fp16 premultiplied weights.
// Last extra block handles exception pixels (flagged, owner skips write).
// ---------------------------------------------------------------------------
__global__ __launch_bounds__(256) void k_prop(
    const float* __restrict__ Fin, const unsigned* __restrict__ Wt,
    const float* __restrict__ feat_fix, const OvfEntry* __restrict__ ovf,
    const int* __restrict__ ovf_cnt, float* __restrict__ Fout, int last) {
    if (blockIdx.x == GRID_MAIN) {
        int cnt = *ovf_cnt;
        if (cnt > OVF_CAP) cnt = OVF_CAP;
        for (int i = threadIdx.x; i < cnt; i += 256) {
            const OvfEntry* e = &ovf[i];
            float s = 0.f;
#pragma unroll
            for (int kk = 0; kk < 9; kk++) {
                int base = e->base[kk];
                s = fmaf(Fin[base],           e->w[kk * 4 + 0], s);
                s = fmaf(Fin[base + 1],       e->w[kk * 4 + 1], s);
                s = fmaf(Fin[base + WWP],     e->w[kk * 4 + 2], s);
                s = fmaf(Fin[base + WWP + 1], e->w[kk * 4 + 3], s);
            }
            int p = e->p;
            if (last) {
                Fout[p] = s;
            } else {
                float ff = feat_fix[p];
                int xx = p % WW;
                int yy = (p / WW) % HH;
                int bb = p / NIMG;
                Fout[(bb * HHP + yy + 2) * WWP + xx + 2] = (ff > 0.f) ? ff : s;
            }
        }
        return;
    }

    int p = blockIdx.x * 256 + threadIdx.x;
    if (p >= NPIX) return;
    int x = p % WW;
    int y = (p / WW) % HH;
    int b = p / NIMG;
    const float* fb = Fin + (size_t)(b * HHP + y) * WWP + x;  // window top-left

    float s = 0.f;
    unsigned uflag = 0;
#pragma unroll
    for (int j = 0; j < 13; j++) {
        unsigned u = Wt[(size_t)j * NPIX + p];
        if (j == 12) uflag = u;
        int c0 = 2 * j;
        int o0 = (c0 / 5) * WWP + (c0 % 5);
        s = fmaf(fb[o0], h2f((unsigned short)(u & 0xffffu)), s);
        if (2 * j + 1 < 25) {
            int c1 = 2 * j + 1;
            int o1 = (c1 / 5) * WWP + (c1 % 5);
            s = fmaf(fb[o1], h2f((unsigned short)(u >> 16)), s);
        }
    }

    if ((uflag >> 16) == 0) {
        if (last) {
            Fout[p] = s;
        } else {
            float ff = feat_fix[p];
            Fout[(b * HHP + y + 2) * WWP + x + 2] = (ff > 0.f) ? ff : s;
        }
    }
}

extern "C" void kernel_launch(void* const* d_in, const int* in_sizes, int n_in,
                              void* d_out, int out_size, void* d_ws, size_t ws_size,
                              hipStream_t stream) {
    const float* feat_init  = (const float*)d_in[0];
    const float* guidance   = (const float*)d_in[1];
    const float* confidence = (const float*)d_in[2];
    const float* feat_fix   = (const float*)d_in[3];
    const float* W_oa       = (const float*)d_in[4];
    const float* b_oa       = (const float*)d_in[5];
    const float* aff_scale  = (const float*)d_in[6];

    char* ws = (char*)d_ws;
    size_t off = 0;
    auto carve = [&](size_t bytes) -> char* {
        char* ptr = ws + off;
        off += (bytes + 511) & ~(size_t)511;
        return ptr;
    };
    float*    Wre  = (float*)carve(24 * 8 * 9 * sizeof(float));
    float*    CPAD = (float*)carve((size_t)BB * CIMG * sizeof(float));
    float*    F0   = (float*)carve((size_t)BB * PIMG * sizeof(float));
    float*    F1   = (float*)carve((size_t)BB * PIMG * sizeof(float));
    unsigned* Wt   = (unsigned*)carve((size_t)13 * NPIX * sizeof(unsigned));
    OvfEntry* OVF  = (OvfEntry*)carve((size_t)OVF_CAP * sizeof(OvfEntry));
    int*      CNT  = (int*)carve(sizeof(int));
    (void)ws_size; (void)in_sizes; (void)n_in; (void)out_size;

    hipMemsetAsync(CNT, 0, sizeof(int), stream);

    int gridc = (BB * CIMG + 255) / 256;
    hipLaunchKernelGGL(k_permute, dim3(1), dim3(256), 0, stream, W_oa, Wre);
    hipLaunchKernelGGL(k_padconf, dim3(gridc), dim3(256), 0, stream,
                       confidence, CPAD);
    hipLaunchKernelGGL(k_precompute, dim3(GRID_MAIN), dim3(256), 0, stream,
                       guidance, CPAD, feat_init, feat_fix, Wre, b_oa,
                       aff_scale, F0, Wt, OVF, CNT);

    float* bufs[2] = {F0, F1};
    int cur = 0;
    for (int it = 0; it < 18; ++it) {
        int last = (it == 17) ? 1 : 0;
        float* outp = last ? (float*)d_out : bufs[cur ^ 1];
        hipLaunchKernelGGL(k_prop, dim3(GRID_MAIN + 1), dim3(256), 0, stream,
                           bufs[cur], Wt, feat_fix, OVF, CNT, outp, last);
        cur ^= 1;
    }
}

// Round 4
// 470.029 us; speedup vs baseline: 1.8762x; 1.1276x over previous
//
#include <hip/hip_runtime.h>
#include <hip/hip_fp16.h>

#define BB 4
#define HH 240
#define WW 1216
#define NIMG (HH * WW)
#define NPIX (BB * NIMG)          // 1,167,360 = 4560 * 256
#define GRID_PRE (NPIX / 256)     // 4560
#define GRID_PROP (NPIX / 512)    // 2280 (2 pixels per thread)

// padded feat layout: image pixel (y,x) lives at (y+2, x+2); 5x5 window of
// pixel (y,x) starts at padded (y, x). Pad cells only ever get weight 0.
#define HHP (HH + 4)              // 244
#define WWP (WW + 4)              // 1220
#define PIMG (HHP * WWP)

// confidence padded with 2 zero rows/cols each side (+1 slack bottom/right)
#define CHP 245
#define CWP 1221
#define CIMG (CHP * CWP)

#define OVF_CAP 65536

typedef __attribute__((ext_vector_type(2))) float float2v;

struct OvfEntry {                 // exception pixel: full 9-tap data
    int p;
    int base[9];                  // padded-layout corner base indices
    float w[36];                  // 4 premultiplied fp32 weights per tap
};

__device__ __forceinline__ unsigned f2h(float f) {
    union { _Float16 h; unsigned short u; } cv;
    cv.h = (_Float16)f;
    return (unsigned)cv.u;
}
__device__ __forceinline__ float h2f(unsigned u) {
    union { unsigned short u; _Float16 h; } cv;
    cv.u = (unsigned short)(u & 0xffffu);
    return (float)cv.h;
}

// ---------------------------------------------------------------------------
__global__ __launch_bounds__(256) void k_permute(const float* __restrict__ W_oa,
                                                 float* __restrict__ Wre) {
    for (int i = threadIdx.x; i < 24 * 8 * 9; i += 256) {
        int o = i / 72;
        int r = i - o * 72;
        int c = r / 9;
        int t = r - c * 9;
        Wre[(c * 9 + t) * 24 + o] = W_oa[i];
    }
}

__global__ __launch_bounds__(256) void k_padconf(const float* __restrict__ conf,
                                                 float* __restrict__ cpad) {
    int i = blockIdx.x * 256 + threadIdx.x;
    if (i >= BB * CIMG) return;
    int xp = i % CWP;
    int yp = (i / CWP) % CHP;
    int b = i / CIMG;
    float v = 0.f;
    int y = yp - 2, x = xp - 2;
    if (y >= 0 && y < HH && x >= 0 && x < WW) v = conf[b * NIMG + y * WW + x];
    cpad[i] = v;
}

__device__ __forceinline__ float fast_tanh(float x) {
    float xc = fminf(fmaxf(x, -15.f), 15.f);
    float e = __expf(2.f * xc);
    return 1.f - 2.f * __builtin_amdgcn_rcpf(e + 1.f);
}

// conv helper: 8->24ch 3x3, packed-f32 accumulators. GUARD = border checks.
template <bool GUARD>
__device__ __forceinline__ void conv_accum(const float* __restrict__ gb,
                                           int y, int x,
                                           const float* __restrict__ Wre,
                                           float2v* acc2) {
#pragma unroll 1
    for (int c = 0; c < 8; c++) {
        const float* gc = gb + c * NIMG;
#pragma unroll
        for (int t = 0; t < 9; t++) {
            int dy = t / 3 - 1;
            int dx = t - (t / 3) * 3 - 1;
            float gv;
            if (GUARD) {
                int yy = y + dy, xx = x + dx;
                gv = (yy >= 0 && yy < HH && xx >= 0 && xx < WW)
                         ? gc[yy * WW + xx] : 0.f;
            } else {
                gv = gc[(y + dy) * WW + (x + dx)];
            }
            const float2v* w2 = (const float2v*)(Wre + (c * 9 + t) * 24);
            float2v g2 = {gv, gv};
#pragma unroll
            for (int o = 0; o < 12; o++)
                acc2[o] = __builtin_elementwise_fma(g2, w2[o], acc2[o]);
        }
    }
}

// ---------------------------------------------------------------------------
// Precompute: conv head -> affinities -> dense 5x5 window weights built in
// REGISTERS via separable outer-product accumulation (no LDS, static idx).
// ---------------------------------------------------------------------------
__global__ __launch_bounds__(256) void k_precompute(
    const float* __restrict__ guid, const float* __restrict__ cpad,
    const float* __restrict__ feat_init, const float* __restrict__ feat_fix,
    const float* __restrict__ Wre, const float* __restrict__ b_oa,
    const float* __restrict__ aff_scale,
    float* __restrict__ F0, unsigned* __restrict__ Wt,
    OvfEntry* __restrict__ ovf, int* __restrict__ ovf_cnt) {
    int p = blockIdx.x * 256 + threadIdx.x;
    int x = p % WW;
    int y = (p / WW) % HH;
    int b = p / NIMG;

    // ---- 3x3 conv, 8 in-ch -> 24 out-ch, zero pad (packed f32) ----
    float2v acc2[12];
    const float2v* b2 = (const float2v*)b_oa;
#pragma unroll
    for (int o = 0; o < 12; o++) acc2[o] = b2[o];

    const float* gb = guid + (size_t)b * 8 * NIMG;
    bool interior = (y >= 1) && (y <= HH - 2) && (x >= 1) && (x <= WW - 2);
    if (interior) conv_accum<false>(gb, y, x, Wre, acc2);
    else          conv_accum<true>(gb, y, x, Wre, acc2);

    float acc[24];
#pragma unroll
    for (int o = 0; o < 24; o++)
        acc[o] = (o & 1) ? acc2[o >> 1].y : acc2[o >> 1].x;

    // ---- TGASS affinity + confidence modulation ----
    float inv_ascale = __builtin_amdgcn_rcpf(aff_scale[0] + 1e-8f);
    const float* cb = cpad + (size_t)b * CIMG;
    float aff[8], ofy[8], ofx[8];
    float asum = 0.f;
#pragma unroll
    for (int k = 0; k < 8; k++) {
        float dy = acc[k];
        float dx = acc[8 + k];
        ofy[k] = dy;
        ofx[k] = dx;
        float a = fast_tanh(acc[16 + k]) * inv_ascale;
        float ys = dy + (float)y;
        float xs = dx + (float)x;
        float y0f = floorf(ys), x0f = floorf(xs);
        float wy = ys - y0f, wx = xs - x0f;
        int ya = (int)(fminf(fmaxf(y0f, -2.f), 241.f)) + 2;
        int yb = (int)(fminf(fmaxf(y0f + 1.f, -2.f), 241.f)) + 2;
        int xa = (int)(fminf(fmaxf(x0f, -2.f), 1217.f)) + 2;
        int xb = (int)(fminf(fmaxf(x0f + 1.f, -2.f), 1217.f)) + 2;
        float v00 = cb[ya * CWP + xa];
        float v01 = cb[ya * CWP + xb];
        float v10 = cb[yb * CWP + xa];
        float v11 = cb[yb * CWP + xb];
        float v = (v00 * (1.f - wx) + v01 * wx) * (1.f - wy)
                + (v10 * (1.f - wx) + v11 * wx) * wy;
        a *= v;
        aff[k] = a;
        asum += fabsf(a);
    }

    float s = fmaxf(asum + 1e-4f, 1.0f);
    float inv = __builtin_amdgcn_rcpf(s);
    float tot = 0.f;
#pragma unroll
    for (int k = 0; k < 8; k++) {
        aff[k] *= inv;
        tot += aff[k];
    }
    float aref = 1.0f - tot;

    // ---- register 5x5 window: separable outer-product accumulation ----
    float w[25];
#pragma unroll
    for (int i = 0; i < 25; i++) w[i] = 0.f;
    bool fits = true;
#pragma unroll
    for (int kk = 0; kk < 9; kk++) {
        float a, dy, dx;
        if (kk < 4)       { a = aff[kk];     dy = ofy[kk];     dx = ofx[kk]; }
        else if (kk == 4) { a = aref;        dy = 0.f;         dx = 0.f; }
        else              { a = aff[kk - 1]; dy = ofy[kk - 1]; dx = ofx[kk - 1]; }
        const int kh = kk / 3 - 1;
        const int kw = kk - (kk / 3) * 3 - 1;
        float fly = floorf(dy), flx = floorf(dx);
        fits = fits && (fly >= -1.f) && (fly <= 0.f)
                    && (flx >= -1.f) && (flx <= 0.f);
        float wy = dy - fly, wx = dx - flx;
        float byf = fly + 1.f, bxf = flx + 1.f;     // in {0,1} on fast path
        int y0 = y + kh + (int)fly;
        int x0 = x + kw + (int)flx;
        float cy0 = (y0 >= 0 && y0 <= HH - 1) ? (1.f - wy) : 0.f;
        float cy1 = (y0 + 1 >= 0 && y0 + 1 <= HH - 1) ? wy : 0.f;
        float cx0 = (x0 >= 0 && x0 <= WW - 1) ? (1.f - wx) : 0.f;
        float cx1 = (x0 + 1 >= 0 && x0 + 1 <= WW - 1) ? wx : 0.f;
        float cya0 = cy0 * a, cya1 = cy1 * a;
        float ry0 = cya0 - byf * cya0;
        float ry1 = fmaf(byf, cya0, cya1 - byf * cya1);
        float ry2 = byf * cya1;
        float rx0 = cx0 - bxf * cx0;
        float rx1 = fmaf(bxf, cx0, cx1 - bxf * cx1);
        float rx2 = bxf * cx1;
        const int base = (kh + 1) * 5 + (kw + 1);   // compile-time
        w[base + 0]  = fmaf(ry0, rx0, w[base + 0]);
        w[base + 1]  = fmaf(ry0, rx1, w[base + 1]);
        w[base + 2]  = fmaf(ry0, rx2, w[base + 2]);
        w[base + 5]  = fmaf(ry1, rx0, w[base + 5]);
        w[base + 6]  = fmaf(ry1, rx1, w[base + 6]);
        w[base + 7]  = fmaf(ry1, rx2, w[base + 7]);
        w[base + 10] = fmaf(ry2, rx0, w[base + 10]);
        w[base + 11] = fmaf(ry2, rx1, w[base + 11]);
        w[base + 12] = fmaf(ry2, rx2, w[base + 12]);
    }

    float yf = (float)y, xf = (float)x;
    if (fits) {
#pragma unroll
        for (int j = 0; j < 13; j++) {
            unsigned lo = f2h(w[2 * j]);
            unsigned hi = (j < 12) ? f2h(w[2 * j + 1]) : 0u;
            Wt[(size_t)j * NPIX + p] = lo | (hi << 16);
        }
    } else {
        int slot = atomicAdd(ovf_cnt, 1);
        if (slot < OVF_CAP) {
            OvfEntry* e = &ovf[slot];
            e->p = p;
#pragma unroll
            for (int kk = 0; kk < 9; kk++) {
                float a, dy, dx;
                if (kk < 4)       { a = aff[kk];     dy = ofy[kk];     dx = ofx[kk]; }
                else if (kk == 4) { a = aref;        dy = 0.f;         dx = 0.f; }
                else              { a = aff[kk - 1]; dy = ofy[kk - 1]; dx = ofx[kk - 1]; }
                float ys = yf + (float)(kk / 3 - 1) + dy;
                float xs = xf + (float)(kk - (kk / 3) * 3 - 1) + dx;
                float y0f = floorf(ys), x0f = floorf(xs);
                float wy = ys - y0f, wx = xs - x0f;
                float y0c = fminf(fmaxf(y0f, -2.f), (float)HH);
                float x0c = fminf(fmaxf(x0f, -2.f), (float)WW);
                int y0 = (int)y0c, x0 = (int)x0c;
                int by = min(max(y0, 0), HH - 2);
                int bx = min(max(x0, 0), WW - 2);
                float cy0 = 0.f, cy1 = 0.f;
                if (y0 >= 0 && y0 <= HH - 1) { if (y0 == by) cy0 = 1.f - wy; else cy1 = 1.f - wy; }
                if (y0 + 1 >= 0 && y0 + 1 <= HH - 1) { if (y0 + 1 == by) cy0 = wy; else cy1 = wy; }
                float cx0 = 0.f, cx1 = 0.f;
                if (x0 >= 0 && x0 <= WW - 1) { if (x0 == bx) cx0 = 1.f - wx; else cx1 = 1.f - wx; }
                if (x0 + 1 >= 0 && x0 + 1 <= WW - 1) { if (x0 + 1 == bx) cx0 = wx; else cx1 = wx; }
                e->base[kk] = (b * HHP + by + 2) * WWP + bx + 2;
                e->w[kk * 4 + 0] = cy0 * cx0 * a;
                e->w[kk * 4 + 1] = cy0 * cx1 * a;
                e->w[kk * 4 + 2] = cy1 * cx0 * a;
                e->w[kk * 4 + 3] = cy1 * cx1 * a;
            }
        }
#pragma unroll
        for (int j = 0; j < 13; j++)
            Wt[(size_t)j * NPIX + p] = (j == 12) ? 0x3C000000u : 0u;
    }

    // ---- F0 = sparse-fix-injected initial feat (padded layout) ----
    float ff = feat_fix[p];
    F0[(b * HHP + y + 2) * WWP + x + 2] = (ff > 0.f) ? ff : feat_init[p];
}

// ---------------------------------------------------------------------------
// One propagation step: dense 5x5 stencil, 2 pixels per thread.
// ---------------------------------------------------------------------------
__global__ __launch_bounds__(256) void k_prop(
    const float* __restrict__ Fin, const unsigned* __restrict__ Wt,
    const float* __restrict__ feat_fix, const OvfEntry* __restrict__ ovf,
    const int* __restrict__ ovf_cnt, float* __restrict__ Fout, int last) {
    if (blockIdx.x == GRID_PROP) {
        int cnt = *ovf_cnt;
        if (cnt > OVF_CAP) cnt = OVF_CAP;
        for (int i = threadIdx.x; i < cnt; i += 256) {
            const OvfEntry* e = &ovf[i];
            float s = 0.f;
#pragma unroll
            for (int kk = 0; kk < 9; kk++) {
                int base = e->base[kk];
                s = fmaf(Fin[base],           e->w[kk * 4 + 0], s);
                s = fmaf(Fin[base + 1],       e->w[kk * 4 + 1], s);
                s = fmaf(Fin[base + WWP],     e->w[kk * 4 + 2], s);
                s = fmaf(Fin[base + WWP + 1], e->w[kk * 4 + 3], s);
            }
            int p = e->p;
            if (last) {
                Fout[p] = s;
            } else {
                float ff = feat_fix[p];
                int xx = p % WW;
                int yy = (p / WW) % HH;
                int bb = p / NIMG;
                Fout[(bb * HHP + yy + 2) * WWP + xx + 2] = (ff > 0.f) ? ff : s;
            }
        }
        return;
    }

    int t0 = blockIdx.x * 256 + threadIdx.x;
    int p = t0 * 2;                         // even; pair (p, p+1), same row
    int x = p % WW;
    int y = (p / WW) % HH;
    int b = p / NIMG;
    const float* fb = Fin + (size_t)(b * HHP + y) * WWP + x;

    uint2 u[13];
#pragma unroll
    for (int j = 0; j < 13; j++)
        u[j] = *(const uint2*)&Wt[(size_t)j * NPIX + p];

    float f[5][6];
#pragma unroll
    for (int r = 0; r < 5; r++) {
        const float* row = fb + r * WWP;
        float2v a0 = *(const float2v*)(row);
        float2v a1 = *(const float2v*)(row + 2);
        float2v a2 = *(const float2v*)(row + 4);
        f[r][0] = a0.x; f[r][1] = a0.y;
        f[r][2] = a1.x; f[r][3] = a1.y;
        f[r][4] = a2.x; f[r][5] = a2.y;
    }

    float s0 = 0.f, s1 = 0.f;
#pragma unroll
    for (int c = 0; c < 25; c++) {
        const int j = c >> 1;
        const int r = c / 5, cc = c - r * 5;
        unsigned w0u = (c & 1) ? (u[j].x >> 16) : u[j].x;
        unsigned w1u = (c & 1) ? (u[j].y >> 16) : u[j].y;
        s0 = fmaf(f[r][cc],     h2f(w0u), s0);
        s1 = fmaf(f[r][cc + 1], h2f(w1u), s1);
    }
    unsigned flag0 = u[12].x >> 16;
    unsigned flag1 = u[12].y >> 16;

    if (last) {
        if (flag0 == 0) Fout[p] = s0;
        if (flag1 == 0) Fout[p + 1] = s1;
    } else {
        float2v ff = *(const float2v*)&feat_fix[p];
        float o0 = (ff.x > 0.f) ? ff.x : s0;
        float o1 = (ff.y > 0.f) ? ff.y : s1;
        float* po = Fout + (size_t)(b * HHP + y + 2) * WWP + x + 2;
        if (flag0 == 0) po[0] = o0;
        if (flag1 == 0) po[1] = o1;
    }
}

extern "C" void kernel_launch(void* const* d_in, const int* in_sizes, int n_in,
                              void* d_out, int out_size, void* d_ws, size_t ws_size,
                              hipStream_t stream) {
    const float* feat_init  = (const float*)d_in[0];
    const float* guidance   = (const float*)d_in[1];
    const float* confidence = (const float*)d_in[2];
    const float* feat_fix   = (const float*)d_in[3];
    const float* W_oa       = (const float*)d_in[4];
    const float* b_oa       = (const float*)d_in[5];
    const float* aff_scale  = (const float*)d_in[6];

    char* ws = (char*)d_ws;
    size_t off = 0;
    auto carve = [&](size_t bytes) -> char* {
        char* ptr = ws + off;
        off += (bytes + 511) & ~(size_t)511;
        return ptr;
    };
    float*    Wre  = (float*)carve(24 * 8 * 9 * sizeof(float));
    float*    CPAD = (float*)carve((size_t)BB * CIMG * sizeof(float));
    float*    F0   = (float*)carve((size_t)BB * PIMG * sizeof(float));
    float*    F1   = (float*)carve((size_t)BB * PIMG * sizeof(float));
    unsigned* Wt   = (unsigned*)carve((size_t)13 * NPIX * sizeof(unsigned));
    OvfEntry* OVF  = (OvfEntry*)carve((size_t)OVF_CAP * sizeof(OvfEntry));
    int*      CNT  = (int*)carve(sizeof(int));
    (void)ws_size; (void)in_sizes; (void)n_in; (void)out_size;

    hipMemsetAsync(CNT, 0, sizeof(int), stream);

    int gridc = (BB * CIMG + 255) / 256;
    hipLaunchKernelGGL(k_permute, dim3(1), dim3(256), 0, stream, W_oa, Wre);
    hipLaunchKernelGGL(k_padconf, dim3(gridc), dim3(256), 0, stream,
                       confidence, CPAD);
    hipLaunchKernelGGL(k_precompute, dim3(GRID_PRE), dim3(256), 0, stream,
                       guidance, CPAD, feat_init, feat_fix, Wre, b_oa,
                       aff_scale, F0, Wt, OVF, CNT);

    float* bufs[2] = {F0, F1};
    int cur = 0;
    for (int it = 0; it < 18; ++it) {
        int last = (it == 17) ? 1 : 0;
        float* outp = last ? (float*)d_out : bufs[cur ^ 1];
        hipLaunchKernelGGL(k_prop, dim3(GRID_PROP + 1), dim3(256), 0, stream,
                           bufs[cur], Wt, feat_fix, OVF, CNT, outp, last);
        cur ^= 1;
    }
}